// Round 4
// baseline (448.832 us; speedup 1.0000x reference)
//
#include <hip/hip_runtime.h>
#include <math.h>

#define N 8192
#define NV4 (N / 4)             // 2048 float4 per full row
#define HV4 (NV4 / 2)           // 1024 float4 per half row
#define RPB 64                  // rows per strip
#define NST (N / RPB)           // 128 row-strips
#define THREADS 256

// ws layout (floats) — every region fully overwritten before read (poison-safe,
// no zero-init, no atomics):
//   degp  : [NST][N]      per-row-strip partial column sums   (4 MB)
//                         (cols<4096 from colsum-left, cols>=4096 from colsum-right)
//   tpart : [NST][2][N]   per-row-strip partial matvec        (8 MB)
//   hpart : [32][2]
#define DEGP_OFF  0
#define TPART_OFF (NST * N)
#define HPART_OFF (TPART_OFF + NST * 2 * N)

// Column sums for one column-half (c4_base = 0 or HV4), all 8192 rows.
__global__ void k_colsum(const float* __restrict__ dsm, float* __restrict__ degp,
                         int c4_base) {
    int chunk = (blockIdx.x + blockIdx.y) & 3;              // column-phase swizzle
    int c4 = c4_base + chunk * THREADS + threadIdx.x;
    int r0 = blockIdx.y * RPB;                              // strip id = blockIdx.y
    const float4* p = (const float4*)dsm;
    float4 acc = {0.f, 0.f, 0.f, 0.f};
#pragma unroll 16
    for (int i = 0; i < RPB; ++i) {
        float4 v = p[(size_t)(r0 + i) * NV4 + c4];
        acc.x += v.x; acc.y += v.y; acc.z += v.z; acc.w += v.w;
    }
    ((float4*)(degp + (size_t)blockIdx.y * N))[c4] = acc;
}

// Weighted partial matvec for one row-half (r_base = 0 or N/2), full 8192 cols.
// Requires degp complete (both colsum halves done).
__global__ void k_matvec(const float* __restrict__ dsm, const float* __restrict__ degp,
                         const float* __restrict__ x, float* __restrict__ tpart,
                         int r_base) {
    __shared__ float sred[4 * RPB];
    __shared__ float sg0[RPB];
    __shared__ float sg1[RPB];
    int r0 = r_base + blockIdx.y * RPB;
    int gst = r0 / RPB;                                     // global strip 0..127

    // Phase A: deg[r] = sum of 128 strip partials for our 64 rows → a[] in LDS.
    {
        int rl = threadIdx.x & 63;
        int q  = threadIdx.x >> 6;
        const float* dp = degp + r0 + rl;
        float s = 0.f;
#pragma unroll 8
        for (int j = 0; j < 32; ++j) s += dp[(size_t)(q * 32 + j) * N];
        sred[q * RPB + rl] = s;
    }
    __syncthreads();
    if (threadIdx.x < RPB) {
        int r = threadIdx.x;
        float d = sred[r] + sred[RPB + r] + sred[2 * RPB + r] + sred[3 * RPB + r];
        float di = d > 0.f ? rsqrtf(d) : 0.f;
        sg0[r] = di * x[r0 + r];
        sg1[r] = di * x[N + r0 + r];
    }
    __syncthreads();

    // Phase B: partial matvec over our 64-row strip, full width.
    int chunk = (blockIdx.x + blockIdx.y) & 7;
    int c4 = chunk * THREADS + threadIdx.x;
    const float4* p = (const float4*)dsm;
    float4 a0 = {0.f, 0.f, 0.f, 0.f};
    float4 a1 = {0.f, 0.f, 0.f, 0.f};
#pragma unroll 16
    for (int i = 0; i < RPB; ++i) {
        float4 v = p[(size_t)(r0 + i) * NV4 + c4];
        float g0 = sg0[i], g1 = sg1[i];
        a0.x += v.x * g0; a0.y += v.y * g0; a0.z += v.z * g0; a0.w += v.w * g0;
        a1.x += v.x * g1; a1.y += v.y * g1; a1.z += v.z * g1; a1.w += v.w * g1;
    }
    ((float4*)(tpart + ((size_t)gst * 2 + 0) * N))[c4] = a0;
    ((float4*)(tpart + ((size_t)gst * 2 + 1) * N))[c4] = a1;
}

__global__ void k_head(const float* __restrict__ degp, const float* __restrict__ tpart,
                       const float* __restrict__ w1, const float* __restrict__ b1,
                       const float* __restrict__ lw1, const float* __restrict__ lb1,
                       const float* __restrict__ lw2, const float* __restrict__ lb2,
                       float* __restrict__ hpart, float* __restrict__ out) {
    __shared__ float swred[8];
    int c = blockIdx.x * THREADS + threadIdx.x;

    float d = 0.f, t0 = 0.f, t1 = 0.f;
#pragma unroll 8
    for (int st = 0; st < NST; ++st) {
        d  += degp[(size_t)st * N + c];
        t0 += tpart[((size_t)st * 2 + 0) * N + c];
        t1 += tpart[((size_t)st * 2 + 1) * N + c];
    }
    float di = d > 0.f ? rsqrtf(d) : 0.f;

    float W1 = w1[0], B1 = b1[0];
    float LW1 = lw1[0], LB1 = lb1[0];
    float LW2 = lw2[0], LB2 = lb2[0];
    float h0 = fmaxf(W1 * di * t0 + B1, 0.f);
    h0 = fmaxf(h0 * LW1 + LB1, 0.f);
    h0 = fmaxf(h0 * LW2 + LB2, 0.f);
    float h1 = fmaxf(W1 * di * t1 + B1, 0.f);
    h1 = fmaxf(h1 * LW1 + LB1, 0.f);
    h1 = fmaxf(h1 * LW2 + LB2, 0.f);

    // softmax over singleton last axis == 1.0 exactly
    out[c] = 1.0f;
    out[N + c] = 1.0f;

    float v0 = h0, v1 = h1;
    for (int off = 32; off > 0; off >>= 1) {
        v0 += __shfl_down(v0, off);
        v1 += __shfl_down(v1, off);
    }
    int wave = threadIdx.x >> 6;
    if ((threadIdx.x & 63) == 0) { swred[wave] = v0; swred[4 + wave] = v1; }
    __syncthreads();
    if (threadIdx.x == 0) {
        hpart[blockIdx.x * 2 + 0] = swred[0] + swred[1] + swred[2] + swred[3];
        hpart[blockIdx.x * 2 + 1] = swred[4] + swred[5] + swred[6] + swred[7];
    }
}

__global__ void k_out(const float* __restrict__ hpart,
                      const float* __restrict__ w2, const float* __restrict__ b2,
                      const float* __restrict__ w3, const float* __restrict__ b3,
                      const float* __restrict__ wv, const float* __restrict__ bv,
                      float* __restrict__ out) {
    int tid = threadIdx.x;
    float s0 = tid < 32 ? hpart[tid * 2 + 0] : 0.f;
    float s1 = tid < 32 ? hpart[tid * 2 + 1] : 0.f;
    for (int off = 16; off > 0; off >>= 1) {
        s0 += __shfl_down(s0, off);
        s1 += __shfl_down(s1, off);
    }
    if (tid == 0) {
        float m0 = s0 * (1.0f / (float)N);
        float m1 = s1 * (1.0f / (float)N);
        float a = fmaxf(m0 * w2[0] + b2[0], 0.f);
        a = fmaxf(a * w3[0] + b3[0], 0.f);
        float b = fmaxf(m1 * w2[0] + b2[0], 0.f);
        b = fmaxf(b * w3[0] + b3[0], 0.f);
        out[2 * N] = fmaxf(a, b) * wv[0] + bv[0];
    }
}

extern "C" void kernel_launch(void* const* d_in, const int* in_sizes, int n_in,
                              void* d_out, int out_size, void* d_ws, size_t ws_size,
                              hipStream_t stream) {
    const float* x   = (const float*)d_in[0];
    const float* dsm = (const float*)d_in[1];
    const float* w1  = (const float*)d_in[2];
    const float* b1  = (const float*)d_in[3];
    const float* lw1 = (const float*)d_in[4];
    const float* lb1 = (const float*)d_in[5];
    const float* lw2 = (const float*)d_in[6];
    const float* lb2 = (const float*)d_in[7];
    const float* w2  = (const float*)d_in[8];
    const float* b2  = (const float*)d_in[9];
    const float* w3  = (const float*)d_in[10];
    const float* b3  = (const float*)d_in[11];
    // d_in[12..13] = wa, ba unused: softmax over a singleton axis == 1.0
    const float* wv  = (const float*)d_in[14];
    const float* bv  = (const float*)d_in[15];

    float* ws    = (float*)d_ws;
    float* degp  = ws + DEGP_OFF;
    float* tpart = ws + TPART_OFF;
    float* hpart = ws + HPART_OFF;

    // Quadrant-ordered schedule: every DSM byte is HBM-filled exactly once;
    // matvec re-reads arrive <=~140 MB of new fills later -> L3 (256 MB) hits.
    dim3 gC(4, NST);   // colsum: 4 column-chunks per half x 128 strips
    dim3 gM(8, NST / 2); // matvec: 8 column-chunks full width x 64 strips (one row-half)
    k_colsum<<<gC, THREADS, 0, stream>>>(dsm, degp, 0);        // fills Q00+Q10
    k_colsum<<<gC, THREADS, 0, stream>>>(dsm, degp, HV4);      // fills Q01+Q11
    k_matvec<<<gM, THREADS, 0, stream>>>(dsm, degp, x, tpart, N / 2);  // Q10(L3)+Q11(L3)
    k_matvec<<<gM, THREADS, 0, stream>>>(dsm, degp, x, tpart, 0);      // Q00(L3)+Q01(L3)
    k_head<<<N / THREADS, THREADS, 0, stream>>>(degp, tpart, w1, b1, lw1, lb1,
                                                lw2, lb2, hpart, (float*)d_out);
    k_out<<<1, 64, 0, stream>>>(hpart, w2, b2, w3, b3, wv, bv, (float*)d_out);
}